// Round 5
// baseline (359.093 us; speedup 1.0000x reference)
//
#include <hip/hip_runtime.h>

#define T_SEQ 512
#define INPUT 14
#define HID 8
#define TC 16
#define NCHUNK (T_SEQ / TC)
#define BN_EPS 1e-5f

typedef float v2f __attribute__((ext_vector_type(2)));

__device__ __forceinline__ float fast_exp2(float x) { return __builtin_amdgcn_exp2f(x); }
__device__ __forceinline__ float fast_rcp(float x)  { return __builtin_amdgcn_rcpf(x); }
__device__ __forceinline__ v2f mk2(float a, float b) { v2f r; r.x = a; r.y = b; return r; }
__device__ __forceinline__ v2f fma2(v2f a, v2f b, v2f c) { return __builtin_elementwise_fma(a, b, c); }

// ds_swizzle fallback for xor16 (LDS pipe)
template <int IMM>
__device__ __forceinline__ float swz(float v) {
    return __int_as_float(__builtin_amdgcn_ds_swizzle(__float_as_int(v), IMM));
}

// DPP cross-lane ops (VALU pipe)
#define DPP_XOR1 0xB1   // quad_perm [1,0,3,2]
#define DPP_XOR2 0x4E   // quad_perm [2,3,0,1]
#define DPP_XOR3 0x1B   // quad_perm [3,2,1,0]
#define DPP_XOR7 0x141  // row_half_mirror: lane ^= 7 within 8-group
#define DPP_XOR8 0x128  // row_ror:8: lane ^= 8 within 16-row
template <int CTRL>
__device__ __forceinline__ float dpp(float v) {
    return __int_as_float(__builtin_amdgcn_update_dpp(
        0, __float_as_int(v), CTRL, 0xF, 0xF, true));
}

// xor16 without the DS pipe: v_permlane16_swap_b32 with src==dst gives, per lane,
// the unordered pair {v, v[lane^16]} in {r[0], r[1]}; r[0]^r[1]^v recovers
// v[lane^16] bit-exactly for EITHER row-pairing polarity.
#if defined(__has_builtin)
#if __has_builtin(__builtin_amdgcn_permlane16_swap)
#define HAVE_PLSWAP 1
#endif
#endif

__device__ __forceinline__ float xor16(float v) {
#ifdef HAVE_PLSWAP
    int a = __float_as_int(v);
    auto r = __builtin_amdgcn_permlane16_swap(a, a, false, false);
    return __int_as_float(((int)r[0]) ^ ((int)r[1]) ^ a);
#else
    return swz<0x401F>(v);
#endif
}

// Butterfly images of h over unit bits {0,1,2}, packed as v2f pairs:
// hx[k] = { h(g^(2k)), h(g^(2k+1)) }  -- 7 DPP movs, all VALU.
__device__ __forceinline__ void butterfly8v(float h, v2f (&hx)[4]) {
    float m1 = dpp<DPP_XOR1>(h);
    float m2 = dpp<DPP_XOR2>(h);
    float m3 = dpp<DPP_XOR3>(h);
    float m7 = dpp<DPP_XOR7>(h);
    float m4 = dpp<DPP_XOR3>(m7);
    float m5 = dpp<DPP_XOR2>(m7);
    float m6 = dpp<DPP_XOR1>(m7);
    hx[0] = mk2(h,  m1);
    hx[1] = mk2(m2, m3);
    hx[2] = mk2(m4, m5);
    hx[3] = mk2(m6, m7);
}

// Block: 256 threads = 4 waves; each wave handles 2 batch elements (32 lanes each).
// Lane g in [0,32): unit = g&7, type = g>>3 (0=i,1=f,2=g,3=o) -- PyTorch gate order.
// Cross-lane: DPP for xor1..8, permlane16_swap for xor16 -- zero DS ops on the
// recurrent chain. Dot products in packed fp32 (v_pk_fma_f32, full rate on gfx950).
__global__ __launch_bounds__(256, 2)
void lstm_forex_kernel(const float* __restrict__ x,
                       const float* __restrict__ Wih1, const float* __restrict__ Whh1,
                       const float* __restrict__ bih1, const float* __restrict__ bhh1,
                       const float* __restrict__ Wih2, const float* __restrict__ Whh2,
                       const float* __restrict__ bih2, const float* __restrict__ bhh2,
                       const float* __restrict__ bn_gamma, const float* __restrict__ bn_beta,
                       const float* __restrict__ bn_mean, const float* __restrict__ bn_var,
                       const float* __restrict__ w1p, const float* __restrict__ b1p,
                       const float* __restrict__ w2p, const float* __restrict__ b2p,
                       float* __restrict__ out)
{
    __shared__ float xbuf[4][2][TC][16];   // [wave][elem][t][14 padded to 16]

    const int tid  = threadIdx.x;
    const int wave = tid >> 6;
    const int lane = tid & 63;
    const int grp  = lane >> 5;          // which of the wave's 2 batch elements
    const int g    = lane & 31;          // gate row index
    const int u    = g & 7;
    const int type = g >> 3;
    const bool b0  = (type & 1) != 0;
    const bool b1  = (type & 2) != 0;

    const int b = blockIdx.x * 8 + wave * 2 + grp;

    // ---- per-lane weight rows; recurrent mats pre-permuted for XOR butterfly,
    //      packed as v2f pairs matching hx[k] = {h(g^2k), h(g^2k+1)} ----
    v2f wi1v[7], wh1v[4], wi2v[4], wh2v[4];
#pragma unroll
    for (int k = 0; k < 7; ++k)
        wi1v[k] = mk2(Wih1[g * INPUT + 2 * k], Wih1[g * INPUT + 2 * k + 1]);
#pragma unroll
    for (int k = 0; k < 4; ++k) {
        int j0 = u ^ (2 * k), j1 = u ^ (2 * k + 1);
        wh1v[k] = mk2(Whh1[g * HID + j0], Whh1[g * HID + j1]);
        wi2v[k] = mk2(Wih2[g * HID + j0], Wih2[g * HID + j1]);
        wh2v[k] = mk2(Whh2[g * HID + j0], Whh2[g * HID + j1]);
    }
    const float bsum1 = bih1[g] + bhh1[g];
    const float bsum2 = bih2[g] + bhh2[g];

    // branch-free activation constants: sigmoid for i,f,o; tanh for g (type==2)
    const float actScale = (type == 2) ? -2.885390082f : -1.4426950408f;
    const float actMul   = (type == 2) ? 2.f : 1.f;
    const float actAdd   = (type == 2) ? -1.f : 0.f;

    // ---- x staging: 448 dwords per wave-chunk (2 elems * 16 t * 14), 7 per lane ----
    const float* gptr[7];
    int loff[7];
#pragma unroll
    for (int it = 0; it < 7; ++it) {
        int d   = it * 64 + lane;       // coalesced flat dword index within wave-chunk
        int es  = d / 224;              // which elem
        int idx = d - es * 224;         // dword within elem's 16x14 chunk
        int tr  = idx / 14;
        int k   = idx - tr * 14;
        int bb  = blockIdx.x * 8 + wave * 2 + es;
        gptr[it] = x + (size_t)bb * (T_SEQ * INPUT) + idx;
        loff[it] = es * (TC * 16) + tr * 16 + k;   // padded LDS layout
    }

    v2f hx1[4], hx2[4];                 // butterfly images of h1, h2 (pair-packed)
    float c1 = 0.f, c2 = 0.f;
#pragma unroll
    for (int k = 0; k < 4; ++k) { hx1[k] = mk2(0.f, 0.f); hx2[k] = mk2(0.f, 0.f); }

    // prefetch chunk 0
    float st[7];
#pragma unroll
    for (int it = 0; it < 7; ++it) { st[it] = *gptr[it]; gptr[it] += TC * INPUT; }

    float (*xw)[TC][16] = xbuf[wave];

    for (int c = 0; c < NCHUNK; ++c) {
        // stage chunk c into LDS (in-order DS per wave makes this visible to reads below)
#pragma unroll
        for (int it = 0; it < 7; ++it) ((float*)xw)[loff[it]] = st[it];
        // prefetch chunk c+1 while computing chunk c
        if (c + 1 < NCHUNK) {
#pragma unroll
            for (int it = 0; it < 7; ++it) { st[it] = *gptr[it]; gptr[it] += TC * INPUT; }
        }
        __builtin_amdgcn_wave_barrier();

#pragma unroll
        for (int t = 0; t < TC; ++t) {
            const float* xrow = &xw[grp][t][0];
            float4 xa = *(const float4*)(xrow + 0);
            float4 xb = *(const float4*)(xrow + 4);
            float4 xc = *(const float4*)(xrow + 8);
            float2 xd = *(const float2*)(xrow + 12);

            // ---- layer 1 x-projection (off the recurrent chain), packed fp32 ----
            v2f acc2v = mk2(bsum1, 0.f);
            acc2v = fma2(mk2(xa.x, xa.y), wi1v[0], acc2v);
            acc2v = fma2(mk2(xa.z, xa.w), wi1v[1], acc2v);
            acc2v = fma2(mk2(xb.x, xb.y), wi1v[2], acc2v);
            acc2v = fma2(mk2(xb.z, xb.w), wi1v[3], acc2v);
            acc2v = fma2(mk2(xc.x, xc.y), wi1v[4], acc2v);
            acc2v = fma2(mk2(xc.z, xc.w), wi1v[5], acc2v);
            acc2v = fma2(mk2(xd.x, xd.y), wi1v[6], acc2v);
            // layer-2 recurrent part (prev h2 -- off chain)
            v2f qv = mk2(bsum2, 0.f);
#pragma unroll
            for (int k = 0; k < 4; ++k) qv = fma2(hx2[k], wh2v[k], qv);
            // layer-1 recurrent butterfly dot
#pragma unroll
            for (int k = 0; k < 4; ++k) acc2v = fma2(hx1[k], wh1v[k], acc2v);
            float acc = acc2v.x + acc2v.y;

            // own-type activation (sigmoid for i,f,o; tanh for g)
            float v0 = fmaf(fast_rcp(1.f + fast_exp2(actScale * acc)), actMul, actAdd);
            // gate exchange: all VALU (DPP + permlane16_swap)
            float v2 = xor16(v0);              // xor 16
            float v1 = dpp<DPP_XOR8>(v0);      // xor 8
            float v3 = dpp<DPP_XOR8>(v2);      // xor 24
            // P = sigmoid(i)*tanh(g), F = sigmoid(f), O = sigmoid(o)
            float P = b0 ? v1 * v3 : v0 * v2;
            float A = b0 ? v0 : v1;
            float Bq = b0 ? v2 : v3;
            float F = b1 ? Bq : A;
            float O = b1 ? A : Bq;
            c1 = fmaf(F, c1, P);
            float th1 = fmaf(fast_rcp(1.f + fast_exp2(-2.885390082f * c1)), 2.f, -1.f);
            float h1u = O * th1;               // every lane holds h1[own unit]
            butterfly8v(h1u, hx1);             // 7 DPP movs (reused next step too)

            // ---- layer 2 ----
            v2f pv = qv;
#pragma unroll
            for (int k = 0; k < 4; ++k) pv = fma2(hx1[k], wi2v[k], pv);
            float acc2 = pv.x + pv.y;

            float u0 = fmaf(fast_rcp(1.f + fast_exp2(actScale * acc2)), actMul, actAdd);
            float u2 = xor16(u0);
            float u1 = dpp<DPP_XOR8>(u0);
            float u3 = dpp<DPP_XOR8>(u2);
            float P2 = b0 ? u1 * u3 : u0 * u2;
            float A2 = b0 ? u0 : u1;
            float B2 = b0 ? u2 : u3;
            float F2 = b1 ? B2 : A2;
            float O2 = b1 ? A2 : B2;
            c2 = fmaf(F2, c2, P2);
            float th2 = fmaf(fast_rcp(1.f + fast_exp2(-2.885390082f * c2)), 2.f, -1.f);
            float h2u = O2 * th2;
            butterfly8v(h2u, hx2);
        }
    }

    // ---- BN (eval) + MLP head, one lane per batch element ----
    // At lane g==0 (u==0): hx2[k] = {h2[2k], h2[2k+1]}.
    if (g == 0) {
        float hd[HID];
#pragma unroll
        for (int j = 0; j < HID; ++j) hd[j] = (j & 1) ? hx2[j >> 1].y : hx2[j >> 1].x;
        float nd[HID];
#pragma unroll
        for (int j = 0; j < HID; ++j) {
            float inv = 1.f / sqrtf(bn_var[j] + BN_EPS);
            nd[j] = bn_gamma[j] * (hd[j] - bn_mean[j]) * inv + bn_beta[j];
        }
        float acc = b2p[0];
#pragma unroll
        for (int m = 0; m < 4; ++m) {
            float s = b1p[m];
#pragma unroll
            for (int j = 0; j < HID; ++j) s = fmaf(nd[j], w1p[m * HID + j], s);
            s = fmaxf(s, 0.f);
            acc = fmaf(s, w2p[m], acc);
        }
        out[b] = acc;
    }
}

extern "C" void kernel_launch(void* const* d_in, const int* in_sizes, int n_in,
                              void* d_out, int out_size, void* d_ws, size_t ws_size,
                              hipStream_t stream) {
    const float* x        = (const float*)d_in[0];
    const float* Wih1     = (const float*)d_in[1];
    const float* Whh1     = (const float*)d_in[2];
    const float* bih1     = (const float*)d_in[3];
    const float* bhh1     = (const float*)d_in[4];
    const float* Wih2     = (const float*)d_in[5];
    const float* Whh2     = (const float*)d_in[6];
    const float* bih2     = (const float*)d_in[7];
    const float* bhh2     = (const float*)d_in[8];
    const float* bn_gamma = (const float*)d_in[9];
    const float* bn_beta  = (const float*)d_in[10];
    const float* bn_mean  = (const float*)d_in[11];
    const float* bn_var   = (const float*)d_in[12];
    const float* w1p      = (const float*)d_in[13];
    const float* b1p      = (const float*)d_in[14];
    const float* w2p      = (const float*)d_in[15];
    const float* b2p      = (const float*)d_in[16];
    float* out = (float*)d_out;

    const int B = in_sizes[0] / (T_SEQ * INPUT);   // 4096
    dim3 grid(B / 8), block(256);
    hipLaunchKernelGGL(lstm_forex_kernel, grid, block, 0, stream,
                       x, Wih1, Whh1, bih1, bhh1, Wih2, Whh2, bih2, bhh2,
                       bn_gamma, bn_beta, bn_mean, bn_var, w1p, b1p, w2p, b2p, out);
}